// Round 1
// baseline (113.240 us; speedup 1.0000x reference)
//
#include <hip/hip_runtime.h>

// B=8, Cin=64, H=W=128, Cout=64, 9 bilinear taps at (i+0.4, j+0.4) == exact 4x4
// conv with zero pad. Implicit GEMM, bf16 MFMA 16x16x32.
//
// v4: DMA staging.
//   - prep kernel materializes xb = bf16 copy of x in conv-ready layout:
//     xb[b][p][y][px][slot][8ch], slot = (chunk + ((px+1)>>2)) & 3  (the LDS
//     cell swizzle baked into memory). One fp32 read + one bf16 conversion per
//     element (was 4x, once per consuming row-strip). Weight-stream build
//     (old make_wb) fused into spare blocks of the same launch.
//   - conv stage = 16x global_load_lds dwordx4 per thread per pass (wave-uniform
//     LDS dest + lane*16B, source pre-swizzled -> LDS image identical to v3).
//     No staging VALU, no staging VGPRs, half the staged bytes (bf16).
//   - per-XCD xb working set ~2.6 MB < 4 MB L2 -> 4x row halo re-read is
//     L2-absorbed; HBM fetch ~17 MB.
//   - compute loop / wb2 stream / epilogue unchanged from v3 (verified).

#define CIN   64
#define COUT  64
#define HH    128
#define WW    128

typedef __attribute__((ext_vector_type(8))) short bf16x8;   // 8 bf16 = 4 VGPRs
typedef __attribute__((ext_vector_type(4))) float f32x4;
typedef __attribute__((ext_vector_type(4))) unsigned int u32x4;

#define GLOBAL_AS __attribute__((address_space(1)))
#define LDS_AS    __attribute__((address_space(3)))

__device__ __forceinline__ unsigned short f2bf(float f) {
  unsigned int u = __float_as_uint(f);
  u = (u + 0x7fffu + ((u >> 16) & 1u)) >> 16;   // RNE
  return (unsigned short)u;
}

#define NREPACK 512   // 512 blocks x 256 thr = 131072 = B*H*W (one thread/px)
#define NWB     16    // 16 blocks x 256 thr = 4096 = Cout*Cin

// ---------------------------------------------------------------------------
// prep: [blocks 0..511] repack x fp32 -> xb bf16 (swizzled conv layout)
//       [blocks 512..527] build wb2 weight stream (identical math to v3)
// ---------------------------------------------------------------------------
__global__ void prep(const float* __restrict__ x,
                     const float* __restrict__ wgt,
                     const float* __restrict__ off,
                     unsigned short* __restrict__ xb,
                     unsigned short* __restrict__ wb2)
{
  if (blockIdx.x < NREPACK) {
    int id = blockIdx.x * 256 + threadIdx.x;    // (b, y, px)
    int px = id & 127;
    int y  = (id >> 7) & 127;
    int b  = id >> 14;
    int q4 = ((px + 1) >> 2) & 3;               // cell-swizzle phase for this px
    unsigned int pk[2][16];                      // [pass][chunk*4 + j/2]
    #pragma unroll
    for (int i = 0; i < 16; ++i) { pk[0][i] = 0u; pk[1][i] = 0u; }
    const float* src = x + ((size_t)b*CIN*HH + y)*WW + px;
    #pragma unroll
    for (int c = 0; c < CIN; ++c) {             // 64 coalesced dword loads
      float v = src[(size_t)c*HH*WW];
      int p = c >> 5, chunk = (c >> 3) & 3, j = c & 7;
      pk[p][chunk*4 + (j >> 1)] |= (unsigned int)f2bf(v) << ((j & 1) * 16);
    }
    #pragma unroll
    for (int p = 0; p < 2; ++p) {
      unsigned short* dst = xb + (((size_t)(b*2 + p)*HH + y)*WW + px)*32;
      #pragma unroll
      for (int chunk = 0; chunk < 4; ++chunk) {
        int slot = (chunk + q4) & 3;            // runtime store addr, static reg idx
        *(u32x4*)(dst + slot*8) = *(u32x4*)&pk[p][chunk*4];
      }
    }
  } else {
    int id = (blockIdx.x - NREPACK) * 256 + threadIdx.x;  // 0..4095
    int o = id >> 6, c = id & 63;
    float W16[16];
    #pragma unroll
    for (int i = 0; i < 16; ++i) W16[i] = 0.f;
    for (int k = 0; k < 9; ++k) {
      float dy = off[2*k], dx = off[2*k+1];
      float fyf = floorf(dy), fxf = floorf(dx);
      int   iy = (int)fyf,   ix = (int)fxf;     // in {0,1,2}
      float fy = dy - fyf,   fx = dx - fxf;
      float wk = wgt[(o*CIN + c)*9 + k];
      W16[(iy  )*4 + ix  ] += wk * (1.f-fy)*(1.f-fx);
      W16[(iy  )*4 + ix+1] += wk * (1.f-fy)*fx;
      W16[(iy+1)*4 + ix  ] += wk * fy*(1.f-fx);
      W16[(iy+1)*4 + ix+1] += wk * fy*fx;
    }
    int p = c >> 5, q = (c >> 3) & 3, j = c & 7;
    int n = o >> 4, m15 = o & 15;
    int lanei = q*16 + m15;
    for (int rs = 0; rs < 16; ++rs)
      wb2[(size_t)(((p*16 + rs)*4 + n)*64 + lanei)*8 + j] = f2bf(W16[rs]);
  }
}

// ---------------------------------------------------------------------------
// conv: WG = 128 threads (2 waves), tile = 1 output row x 128 px x 64 Cout.
// LDS tile: 4 rows x 132 cols x 32 ch(bf16) with XOR slot swizzle. 33792 B.
// Staging via global_load_lds dwordx4 from pre-swizzled xb.
// ---------------------------------------------------------------------------
__global__ __launch_bounds__(128, 2)   // 2 waves/EU -> 4 blocks/CU
void conv_mfma(const unsigned short* __restrict__ xb,
               const unsigned short* __restrict__ wb2,
               float* __restrict__ out)
{
  __shared__ unsigned short tile[4 * 132 * 32]; // 33792 B (also epilogue f32 buf)

  const int wg  = blockIdx.x;                   // 1024
  const int xcd = wg & 7;
  const int i8  = wg >> 3;                      // 0..127
  const int b   = i8 >> 4;
  const int y0  = xcd * 16 + (i8 & 15);         // XCD-local 16-row band
  const int t    = threadIdx.x;
  const int wave = t >> 6;                      // 0..1
  const int lane = t & 63;
  const int m15  = lane & 15;
  const int q    = lane >> 4;

  f32x4 acc[4][4];
  #pragma unroll
  for (int mi = 0; mi < 4; ++mi)
    #pragma unroll
    for (int n = 0; n < 4; ++n)
      acc[mi][n] = (f32x4){0.f, 0.f, 0.f, 0.f};

  const size_t rowstride = (size_t)WW * 32;     // shorts per xb row (8 KB)

  #pragma unroll
  for (int p = 0; p < 2; ++p) {                 // channel pass: c in [32p, 32p+32)
    if (p) __syncthreads();                     // pass-0 tile reads complete

    if (p == 0) {                               // zero edge cells (cols 0,129,130,131)
      int row = t >> 5, rem = t & 31;
      int csel = rem >> 3;
      int col  = (csel == 0) ? 0 : (128 + csel);
      int w8   = rem & 7;
      *(unsigned long long*)&tile[(row*132 + col)*32 + w8*4] = 0ull;
    }

    // ---- stage: 32 segs = 4 rows x 8 x 1KB; one gload_lds dwordx4 per seg ----
    const unsigned short* xbase = xb + (size_t)(b*2 + p)*HH*rowstride;
    #pragma unroll
    for (int it = 0; it < 16; ++it) {
      int g   = it*2 + wave;                    // 0..31
      int row = g >> 3;                         // 0..3
      int seg = g & 7;                          // 1 KB segment within row
      int gy  = y0 + row - 1;                   // -1..129
      unsigned short* ldsdst = &tile[(row*132 + 1)*32 + seg*512];
      if ((unsigned)gy < (unsigned)HH) {
        const unsigned short* src = xbase + (size_t)gy*rowstride + seg*512 + lane*8;
        __builtin_amdgcn_global_load_lds((const GLOBAL_AS unsigned int*)src,
                                         (LDS_AS unsigned int*)ldsdst, 16, 0, 0);
      } else if (p == 0) {                      // out-of-range row: zero once;
        *(u32x4*)(ldsdst + lane*8) = (u32x4){0u,0u,0u,0u};   // pass 1 keeps it
      }
    }
    __syncthreads();

    // ---- compute: 16 rs steps; B = contiguous stream loads, A = swizzled LDS ----
    const unsigned short* wstream = wb2 + (size_t)p*16*4*512 + lane*8;
    #pragma unroll
    for (int rs = 0; rs < 16; ++rs) {
      const int r = rs >> 2, s = rs & 3;
      bf16x8 bfr[4];
      #pragma unroll
      for (int n = 0; n < 4; ++n)
        bfr[n] = *(const bf16x8*)(wstream + (rs*4 + n)*512);
      bf16x8 afr[4];
      #pragma unroll
      for (int mi = 0; mi < 4; ++mi) {
        int pos  = wave*64 + mi*16 + m15 + s;
        int slot = (q + (pos >> 2)) & 3;
        afr[mi] = *(const bf16x8*)(&tile[((r*132 + pos)*4 + slot)*8]);
      }
      #pragma unroll
      for (int mi = 0; mi < 4; ++mi)
        #pragma unroll
        for (int n = 0; n < 4; ++n)
          acc[mi][n] = __builtin_amdgcn_mfma_f32_16x16x32_bf16(afr[mi], bfr[n], acc[mi][n], 0, 0, 0);
    }
  }

  // ---- epilogue: transpose through LDS for coalesced stores ----
  __syncthreads();                              // all tile reads done
  float* epi = (float*)tile;                    // [64 o][132 px] = 33792 B
  #pragma unroll
  for (int mi = 0; mi < 4; ++mi)
    #pragma unroll
    for (int n = 0; n < 4; ++n) {
      int o  = n*16 + m15;
      int px = wave*64 + mi*16 + q*4;           // D row = q*4 + reg
      *(f32x4*)&epi[o*132 + px] = acc[mi][n];
    }
  __syncthreads();
  #pragma unroll
  for (int i = 0; i < 16; ++i) {
    int o  = i*4 + (t >> 5);
    int px = (t & 31) * 4;
    f32x4 v = *(const f32x4*)&epi[o*132 + px];
    *(f32x4*)&out[(((size_t)(b*COUT + o))*HH + y0)*WW + px] = v;
  }
}

// ---------------------------------------------------------------------------
extern "C" void kernel_launch(void* const* d_in, const int* in_sizes, int n_in,
                              void* d_out, int out_size, void* d_ws, size_t ws_size,
                              hipStream_t stream)
{
  const float* x   = (const float*)d_in[0];   // [8,64,128,128] fp32
  const float* wgt = (const float*)d_in[1];   // [64,64,9] fp32
  const float* off = (const float*)d_in[2];   // [9,2] fp32
  float* out = (float*)d_out;                 // [8,64,128,128] fp32
  unsigned short* wb2 = (unsigned short*)d_ws;            // 128 KB weight stream
  unsigned short* xb  = (unsigned short*)d_ws + 65536;    // 16.78 MB bf16 image

  prep<<<NREPACK + NWB, 256, 0, stream>>>(x, wgt, off, xb, wb2);
  conv_mfma<<<1024, 128, 0, stream>>>(xb, wb2, out);
}